// Round 11
// baseline (287.202 us; speedup 1.0000x reference)
//
#include <hip/hip_runtime.h>
#include <hip/hip_bf16.h>
#include <hip/hip_fp16.h>
#include <math.h>

// Problem: h = z @ W + b  (z [N,256] fp32, W [256,256] fp32, b [256])
//          out[e] = sigmoid(dot(h[src[e]], h[dst[e]]))  for E edges
// N = 100000, E = 300000, D = 256.
//
// R23: MEASUREMENT ROUND. Gemm reverted byte-exact to R19 (best total,
// 202.35us). Edge kernel launched 3x (idempotent, deterministic) so
// E_warm = (total - 202.4)/2. The rocprof top-5 cutoff has hidden all
// our kernels under the harness's 60us fill since R19; the edge time
// was never measured, only inferred (~55us zero-reuse floor), yet h
// (51.2MB) fits L3 (256MB) which predicts ~15-20us if L3-served. The
// two worlds need opposite next moves (src-bucketing vs not) -- buy
// the number. R22 post-mortem: B-in-regs null; 7 gemm theories dead;
// gemm pinned at ~50us, 2x over its 24us HBM floor, limiter unknown.

#define D_DIM 256
#define NBLK 256

typedef __attribute__((ext_vector_type(8))) _Float16 half8;
typedef __attribute__((ext_vector_type(4))) _Float16 half4;
typedef __attribute__((ext_vector_type(4))) float f32x4;

__device__ half8 g_Wf[8 * 256 * 4];   // [kb][fn][qd][fr], 128 KB

// 8192 threads: t -> (kb, qd, n), n fastest => coalesced row reads of W.
// frag(n = fn*16+fr, qd)[j] = W[(kb*32 + qd*8 + j)*256 + n]
__global__ __launch_bounds__(256) void pack_w_kernel(const float* __restrict__ W) {
  int t = blockIdx.x * 256 + threadIdx.x;   // 0..8191
  int kb = t >> 10;
  int qd = (t >> 8) & 3;
  int n  = t & 255;
  int fn = n >> 4;
  int fr = n & 15;
  half8 o;
#pragma unroll
  for (int j = 0; j < 8; j++)
    o[j] = (_Float16)W[(size_t)(kb * 32 + qd * 8 + j) * D_DIM + n];
  g_Wf[kb * 1024 + fn * 64 + qd * 16 + fr] = o;
}

// cvt two float4 (fp32 z data) and ds_write as fp16 into swizzled A-tile.
// Thread t covers strip rows t>>6 and (t>>6)+8. Swizzle: phys = row*512
// + (inner ^ ((row&7)<<4)).
__device__ inline void stage_write(char* tile, int tid, float4 A, float4 B) {
  int row = tid >> 6;                 // 0..7
  int inner = (tid & 63) * 8;         // byte offset in 512B fp16 row
  int sw = (row & 7) << 4;
  half4 p0, p1;
  p0[0] = (_Float16)A.x; p0[1] = (_Float16)A.y;
  p0[2] = (_Float16)A.z; p0[3] = (_Float16)A.w;
  p1[0] = (_Float16)B.x; p1[1] = (_Float16)B.y;
  p1[2] = (_Float16)B.z; p1[3] = (_Float16)B.w;
  *(half4*)(tile + row * 512 + (inner ^ sw)) = p0;
  *(half4*)(tile + (row + 8) * 512 + (inner ^ sw)) = p1;
}

__global__ __launch_bounds__(512) void gemm_mfma_kernel(
    const float* __restrict__ z, const float* __restrict__ b,
    __half* __restrict__ h, int nrows) {
  // 128KB resident B frags + 2 x 8KB A-tile double buffer = 144KB.
  __shared__ char smem[147456];
  const int tid = threadIdx.x;
  const int lane = tid & 63;
  const int wv = tid >> 6;          // 0..7 (owns cols wv*32 .. +31)
  const int fr = lane & 15;
  const int qd = lane >> 4;

  // ---- one-time B stage: linear 128KB via global_load_lds
  {
    const char* gsrc = (const char*)g_Wf;
#pragma unroll
    for (int rnd = 0; rnd < 16; rnd++) {
      int off = rnd * 8192 + wv * 1024;
      __builtin_amdgcn_global_load_lds(
          (const __attribute__((address_space(1))) void*)(gsrc + off + lane * 16),
          (__attribute__((address_space(3))) void*)(smem + off),
          16, 0, 0);
    }
  }
  float bias0 = b[wv * 32 + fr];
  float bias1 = b[wv * 32 + 16 + fr];

  char* atile0 = smem + 131072;
  char* atile1 = smem + 139264;
  const char* zb = (const char*)z;
  const int nstrips = (nrows + 15) >> 4;   // 6250 (N%16==0 here)

  // ---- prologue: stage strip s0 into atile0 (linear loads, 1KB/instr)
  int s0 = blockIdx.x;
  float4 ld0, ld1;
  {
    const char* sb = zb + (size_t)s0 * 16384;
    ld0 = *(const float4*)(sb + tid * 16);
    ld1 = *(const float4*)(sb + 8192 + tid * 16);
  }
  stage_write(atile0, tid, ld0, ld1);
  __syncthreads();   // B + A(s0) resident & visible

  const half8* bw = (const half8*)smem;
  int cur = 0;

#pragma unroll 1
  for (int s = s0; s < nstrips; s += NBLK) {
    char* at = cur ? atile1 : atile0;
    char* an = cur ? atile0 : atile1;
    const bool hasnext = (s + NBLK) < nstrips;

    // issue next strip's loads (contiguous; consumed after epilogue)
    if (hasnext) {
      const char* sb = zb + (size_t)(s + NBLK) * 16384;
      ld0 = *(const float4*)(sb + tid * 16);
      ld1 = *(const float4*)(sb + 8192 + tid * 16);
    }
    asm volatile("" ::: "memory");   // pin issue point (R13 lesson)

    // ---- MFMA: af from swizzled A-tile, bf from resident B
    f32x4 acc0 = (f32x4)0.f, acc1 = (f32x4)0.f;
    const char* abase = at + fr * 512;
    const int sw = (fr & 7) << 4;
#pragma unroll
    for (int kb = 0; kb < 8; kb++) {
      half8 af = *(const half8*)(abase + ((kb * 64 + qd * 16) ^ sw));
      half8 bf0 = bw[kb * 1024 + (2 * wv) * 64 + lane];
      half8 bf1 = bw[kb * 1024 + (2 * wv + 1) * 64 + lane];
      acc0 = __builtin_amdgcn_mfma_f32_16x16x32_f16(af, bf0, acc0, 0, 0, 0);
      acc1 = __builtin_amdgcn_mfma_f32_16x16x32_f16(af, bf1, acc1, 0, 0, 0);
    }
    __syncthreads();   // all waves done reading at -> safe to reuse

    // ---- epilogue: own 1KB region of the consumed tile (rows 16 x 64B)
    __half* et = (__half*)(at + wv * 1024);
#pragma unroll
    for (int r = 0; r < 4; r++) {
      et[(qd * 4 + r) * 32 + fr]      = __float2half(acc0[r] + bias0);
      et[(qd * 4 + r) * 32 + 16 + fr] = __float2half(acc1[r] + bias1);
    }
    int row = lane >> 2, c = lane & 3;
    float4 v = *(const float4*)((const char*)et + row * 64 + c * 16);

    // consume next loads into the other tile (latency covered by MFMA+epi)
    if (hasnext) stage_write(an, tid, ld0, ld1);

    // coalesced 64B-chunk store of own column slice (fire & forget)
    int grow = s * 16 + row;
    if (grow < nrows)
      *(float4*)((char*)h + (size_t)grow * 512 + wv * 64 + c * 16) = v;

    cur ^= 1;
    __syncthreads();   // next iter's tile staged & visible; epi reads done
  }
}

// 1 wave per 8 edges; per edge ONE 1KB load instr: lanes 0-31 cover the
// 512B src row, lanes 32-63 the dst row. Pair via shfl_xor(32), butterfly.
__global__ __launch_bounds__(256) void edge_dot_kernel(
    const int* __restrict__ ei, const __half* __restrict__ h,
    float* __restrict__ out, int E) {
  int wid = (blockIdx.x * blockDim.x + threadIdx.x) >> 6;
  int lane = threadIdx.x & 63;
  int ebase = wid * 8;
  if (ebase >= E) return;
  const int half = lane >> 5;      // 0=src row, 1=dst row
  const int off = lane & 31;       // float4 chunk within the 512B row

  float4 v[8];
#pragma unroll
  for (int q = 0; q < 8; q++) {
    int e = ebase + q;
    e = e < E ? e : (E - 1);
    int node = half ? ei[E + e] : ei[e];   // uniform per 32-lane half
    v[q] = *(const float4*)((const __half*)h + (size_t)node * D_DIM + off * 8);
  }

  float res = 0.f;
#pragma unroll
  for (int q = 0; q < 8; q++) {
    float4 w;
    w.x = __shfl_xor(v[q].x, 32);
    w.y = __shfl_xor(v[q].y, 32);
    w.z = __shfl_xor(v[q].z, 32);
    w.w = __shfl_xor(v[q].w, 32);
    const __half2* a2 = (const __half2*)&v[q];
    const __half2* b2 = (const __half2*)&w;
    float part = 0.f;
#pragma unroll
    for (int j = 0; j < 4; j++) {
      float2 fa = __half22float2(a2[j]);
      float2 fb = __half22float2(b2[j]);
      part += fa.x * fb.x + fa.y * fb.y;
    }
#pragma unroll
    for (int m = 1; m <= 16; m <<= 1) part += __shfl_xor(part, m);
    res = (lane == q) ? part : res;    // lanes 0..7 collect the 8 results
  }
  if (lane < 8) {
    int e = ebase + lane;
    if (e < E) out[e] = 1.0f / (1.0f + __expf(-res));
  }
}

extern "C" void kernel_launch(void* const* d_in, const int* in_sizes, int n_in,
                              void* d_out, int out_size, void* d_ws, size_t ws_size,
                              hipStream_t stream) {
  const float* z  = (const float*)d_in[0];
  const int*   ei = (const int*)d_in[1];
  const float* W  = (const float*)d_in[2];
  const float* b  = (const float*)d_in[3];
  float* out = (float*)d_out;
  __half* h  = (__half*)d_ws;   // 100000*256*2 = 51.2 MB scratch

  const int nnodes = in_sizes[0] / D_DIM;
  const int E = in_sizes[1] / 2;

  pack_w_kernel<<<32, 256, 0, stream>>>(W);

  gemm_mfma_kernel<<<NBLK, 512, 0, stream>>>(z, b, h, nnodes);

  int waves = (E + 7) / 8;                        // 1 wave per 8 edges
  dim3 grid_edge(((size_t)waves * 64 + 255) / 256);
  // MEASUREMENT: 3 idempotent launches. E_warm = (total - 202.4)/2.
  edge_dot_kernel<<<grid_edge, 256, 0, stream>>>(ei, h, out, E);
  edge_dot_kernel<<<grid_edge, 256, 0, stream>>>(ei, h, out, E);
  edge_dot_kernel<<<grid_edge, 256, 0, stream>>>(ei, h, out, E);
}

// Round 13
// 209.469 us; speedup vs baseline: 1.3711x; 1.3711x over previous
//
#include <hip/hip_runtime.h>
#include <hip/hip_bf16.h>
#include <hip/hip_fp16.h>
#include <math.h>

// Problem: h = z @ W + b  (z [N,256] fp32, W [256,256] fp32, b [256])
//          out[e] = sigmoid(dot(h[src[e]], h[dst[e]]))  for E edges
// N = 100000, E = 300000, D = 256.
//
// R25 (= R24 with compile fix): non-temporal h stores. R23's 3x-edge
// measurement closed the budget: edge_warm = 42.4us but edge_COLD
// ~=140us -- the dominant term all along (gemm ~50, fill harness-fixed).
// Mechanism: gemm leaves h DIRTY in per-XCD L2s; the node-random gather
// reads ~7/8 of rows from a DIFFERENT XCD -> L3-mediated dirty-line
// writeback per miss (~2.2 TB/s). Warm passes read clean L3 data at
// 7.2 TB/s. Fix: stream h stores via __builtin_nontemporal_store so
// lines land clean in L3/HBM; edge's first pass then reads at the warm
// rate. Compile fix vs R24: the builtin requires ext_vector_type, not
// HIP_vector_type -> epilogue readback/store use f32x4. Gemm otherwise
// byte-identical to R19; edge single launch; single-variable round.

#define D_DIM 256
#define NBLK 256

typedef __attribute__((ext_vector_type(8))) _Float16 half8;
typedef __attribute__((ext_vector_type(4))) _Float16 half4;
typedef __attribute__((ext_vector_type(4))) float f32x4;

__device__ half8 g_Wf[8 * 256 * 4];   // [kb][fn][qd][fr], 128 KB

// 8192 threads: t -> (kb, qd, n), n fastest => coalesced row reads of W.
// frag(n = fn*16+fr, qd)[j] = W[(kb*32 + qd*8 + j)*256 + n]
__global__ __launch_bounds__(256) void pack_w_kernel(const float* __restrict__ W) {
  int t = blockIdx.x * 256 + threadIdx.x;   // 0..8191
  int kb = t >> 10;
  int qd = (t >> 8) & 3;
  int n  = t & 255;
  int fn = n >> 4;
  int fr = n & 15;
  half8 o;
#pragma unroll
  for (int j = 0; j < 8; j++)
    o[j] = (_Float16)W[(size_t)(kb * 32 + qd * 8 + j) * D_DIM + n];
  g_Wf[kb * 1024 + fn * 64 + qd * 16 + fr] = o;
}

// cvt two float4 (fp32 z data) and ds_write as fp16 into swizzled A-tile.
// Thread t covers strip rows t>>6 and (t>>6)+8. Swizzle: phys = row*512
// + (inner ^ ((row&7)<<4)).
__device__ inline void stage_write(char* tile, int tid, float4 A, float4 B) {
  int row = tid >> 6;                 // 0..7
  int inner = (tid & 63) * 8;         // byte offset in 512B fp16 row
  int sw = (row & 7) << 4;
  half4 p0, p1;
  p0[0] = (_Float16)A.x; p0[1] = (_Float16)A.y;
  p0[2] = (_Float16)A.z; p0[3] = (_Float16)A.w;
  p1[0] = (_Float16)B.x; p1[1] = (_Float16)B.y;
  p1[2] = (_Float16)B.z; p1[3] = (_Float16)B.w;
  *(half4*)(tile + row * 512 + (inner ^ sw)) = p0;
  *(half4*)(tile + (row + 8) * 512 + (inner ^ sw)) = p1;
}

__global__ __launch_bounds__(512) void gemm_mfma_kernel(
    const float* __restrict__ z, const float* __restrict__ b,
    __half* __restrict__ h, int nrows) {
  // 128KB resident B frags + 2 x 8KB A-tile double buffer = 144KB.
  __shared__ char smem[147456];
  const int tid = threadIdx.x;
  const int lane = tid & 63;
  const int wv = tid >> 6;          // 0..7 (owns cols wv*32 .. +31)
  const int fr = lane & 15;
  const int qd = lane >> 4;

  // ---- one-time B stage: linear 128KB via global_load_lds
  {
    const char* gsrc = (const char*)g_Wf;
#pragma unroll
    for (int rnd = 0; rnd < 16; rnd++) {
      int off = rnd * 8192 + wv * 1024;
      __builtin_amdgcn_global_load_lds(
          (const __attribute__((address_space(1))) void*)(gsrc + off + lane * 16),
          (__attribute__((address_space(3))) void*)(smem + off),
          16, 0, 0);
    }
  }
  float bias0 = b[wv * 32 + fr];
  float bias1 = b[wv * 32 + 16 + fr];

  char* atile0 = smem + 131072;
  char* atile1 = smem + 139264;
  const char* zb = (const char*)z;
  const int nstrips = (nrows + 15) >> 4;   // 6250 (N%16==0 here)

  // ---- prologue: stage strip s0 into atile0 (linear loads, 1KB/instr)
  int s0 = blockIdx.x;
  float4 ld0, ld1;
  {
    const char* sb = zb + (size_t)s0 * 16384;
    ld0 = *(const float4*)(sb + tid * 16);
    ld1 = *(const float4*)(sb + 8192 + tid * 16);
  }
  stage_write(atile0, tid, ld0, ld1);
  __syncthreads();   // B + A(s0) resident & visible

  const half8* bw = (const half8*)smem;
  int cur = 0;

#pragma unroll 1
  for (int s = s0; s < nstrips; s += NBLK) {
    char* at = cur ? atile1 : atile0;
    char* an = cur ? atile0 : atile1;
    const bool hasnext = (s + NBLK) < nstrips;

    // issue next strip's loads (contiguous; consumed after epilogue)
    if (hasnext) {
      const char* sb = zb + (size_t)(s + NBLK) * 16384;
      ld0 = *(const float4*)(sb + tid * 16);
      ld1 = *(const float4*)(sb + 8192 + tid * 16);
    }
    asm volatile("" ::: "memory");   // pin issue point (R13 lesson)

    // ---- MFMA: af from swizzled A-tile, bf from resident B
    f32x4 acc0 = (f32x4)0.f, acc1 = (f32x4)0.f;
    const char* abase = at + fr * 512;
    const int sw = (fr & 7) << 4;
#pragma unroll
    for (int kb = 0; kb < 8; kb++) {
      half8 af = *(const half8*)(abase + ((kb * 64 + qd * 16) ^ sw));
      half8 bf0 = bw[kb * 1024 + (2 * wv) * 64 + lane];
      half8 bf1 = bw[kb * 1024 + (2 * wv + 1) * 64 + lane];
      acc0 = __builtin_amdgcn_mfma_f32_16x16x32_f16(af, bf0, acc0, 0, 0, 0);
      acc1 = __builtin_amdgcn_mfma_f32_16x16x32_f16(af, bf1, acc1, 0, 0, 0);
    }
    __syncthreads();   // all waves done reading at -> safe to reuse

    // ---- epilogue: own 1KB region of the consumed tile (rows 16 x 64B)
    __half* et = (__half*)(at + wv * 1024);
#pragma unroll
    for (int r = 0; r < 4; r++) {
      et[(qd * 4 + r) * 32 + fr]      = __float2half(acc0[r] + bias0);
      et[(qd * 4 + r) * 32 + 16 + fr] = __float2half(acc1[r] + bias1);
    }
    int row = lane >> 2, c = lane & 3;
    f32x4 v = *(const f32x4*)((const char*)et + row * 64 + c * 16);

    // consume next loads into the other tile (latency covered by MFMA+epi)
    if (hasnext) stage_write(an, tid, ld0, ld1);

    // NON-TEMPORAL store: h lines land clean in L3/HBM instead of dirty
    // in this XCD's L2 -> edge's cross-XCD gather avoids per-line
    // writeback serialization (R23: edge_cold 142us vs warm 42us).
    int grow = s * 16 + row;
    if (grow < nrows)
      __builtin_nontemporal_store(
          v, (f32x4*)((char*)h + (size_t)grow * 512 + wv * 64 + c * 16));

    cur ^= 1;
    __syncthreads();   // next iter's tile staged & visible; epi reads done
  }
}

// 1 wave per 8 edges; per edge ONE 1KB load instr: lanes 0-31 cover the
// 512B src row, lanes 32-63 the dst row. Pair via shfl_xor(32), butterfly.
__global__ __launch_bounds__(256) void edge_dot_kernel(
    const int* __restrict__ ei, const __half* __restrict__ h,
    float* __restrict__ out, int E) {
  int wid = (blockIdx.x * blockDim.x + threadIdx.x) >> 6;
  int lane = threadIdx.x & 63;
  int ebase = wid * 8;
  if (ebase >= E) return;
  const int half = lane >> 5;      // 0=src row, 1=dst row
  const int off = lane & 31;       // float4 chunk within the 512B row

  float4 v[8];
#pragma unroll
  for (int q = 0; q < 8; q++) {
    int e = ebase + q;
    e = e < E ? e : (E - 1);
    int node = half ? ei[E + e] : ei[e];   // uniform per 32-lane half
    v[q] = *(const float4*)((const __half*)h + (size_t)node * D_DIM + off * 8);
  }

  float res = 0.f;
#pragma unroll
  for (int q = 0; q < 8; q++) {
    float4 w;
    w.x = __shfl_xor(v[q].x, 32);
    w.y = __shfl_xor(v[q].y, 32);
    w.z = __shfl_xor(v[q].z, 32);
    w.w = __shfl_xor(v[q].w, 32);
    const __half2* a2 = (const __half2*)&v[q];
    const __half2* b2 = (const __half2*)&w;
    float part = 0.f;
#pragma unroll
    for (int j = 0; j < 4; j++) {
      float2 fa = __half22float2(a2[j]);
      float2 fb = __half22float2(b2[j]);
      part += fa.x * fb.x + fa.y * fb.y;
    }
#pragma unroll
    for (int m = 1; m <= 16; m <<= 1) part += __shfl_xor(part, m);
    res = (lane == q) ? part : res;    // lanes 0..7 collect the 8 results
  }
  if (lane < 8) {
    int e = ebase + lane;
    if (e < E) out[e] = 1.0f / (1.0f + __expf(-res));
  }
}

extern "C" void kernel_launch(void* const* d_in, const int* in_sizes, int n_in,
                              void* d_out, int out_size, void* d_ws, size_t ws_size,
                              hipStream_t stream) {
  const float* z  = (const float*)d_in[0];
  const int*   ei = (const int*)d_in[1];
  const float* W  = (const float*)d_in[2];
  const float* b  = (const float*)d_in[3];
  float* out = (float*)d_out;
  __half* h  = (__half*)d_ws;   // 100000*256*2 = 51.2 MB scratch

  const int nnodes = in_sizes[0] / D_DIM;
  const int E = in_sizes[1] / 2;

  pack_w_kernel<<<32, 256, 0, stream>>>(W);

  gemm_mfma_kernel<<<NBLK, 512, 0, stream>>>(z, b, h, nnodes);

  int waves = (E + 7) / 8;                        // 1 wave per 8 edges
  dim3 grid_edge(((size_t)waves * 64 + 255) / 256);
  edge_dot_kernel<<<grid_edge, 256, 0, stream>>>(ei, h, out, E);
}